// Round 1
// baseline (258.129 us; speedup 1.0000x reference)
//
#include <hip/hip_runtime.h>

// DCT encoder as GEMM: C[k][j] = sum_p A[k][p] * X[j][p]
//   A = (2/32 * factors[k]) * kernels[k][p]   (M=1024, K=1024, bf16, scale folded)
//   X[j][p] = ycbcr2m1(rgb)[b,c, m*32+x, n*32+y], j=((b*3+c)*16+m)*16+n, p=x*32+y
// out[b, c*1024+k, m, n] -> flat = (b*3+c)*262144 + k*256 + (j&255)

typedef __bf16 bf16x8 __attribute__((ext_vector_type(8)));
typedef float  f32x4  __attribute__((ext_vector_type(4)));

#define GLOAD_LDS16(gp, lp)                                                      \
    __builtin_amdgcn_global_load_lds(                                            \
        (const __attribute__((address_space(1))) void*)(gp),                     \
        (__attribute__((address_space(3))) void*)(lp), 16, 0, 0)

__device__ __forceinline__ unsigned short f2bf(float f) {
    union { float f; unsigned u; } v; v.f = f;
    unsigned u = v.u;
    u += 0x7fffu + ((u >> 16) & 1u);   // round-to-nearest-even
    return (unsigned short)(u >> 16);
}

// ---- kernel 1: rgb (32,3,512,512) f32 -> X[j][p] bf16 in workspace ----------
__global__ __launch_bounds__(256) void prep_kernel(const float* __restrict__ rgb,
                                                   unsigned short* __restrict__ X) {
    int t  = blockIdx.x * 256 + threadIdx.x;   // over (b, h, w/4): 32*512*128
    int w4 = t & 127;
    int h  = (t >> 7) & 511;
    int b  = t >> 16;
    size_t base = (size_t)b * 786432 + (size_t)h * 512 + (size_t)w4 * 4;
    float4 rv = *(const float4*)(rgb + base);
    float4 gv = *(const float4*)(rgb + base + 262144);
    float4 bv = *(const float4*)(rgb + base + 524288);

    int m = h >> 5, x = h & 31;
    int w0 = w4 * 4;
    int n = w0 >> 5, yc = w0 & 31;
    // j for c=0:
    size_t j0  = ((size_t)(b * 3) * 16 + (size_t)m) * 16 + (size_t)n;
    size_t off = j0 * 1024 + (size_t)x * 32 + (size_t)yc;

    float r[4]  = {rv.x, rv.y, rv.z, rv.w};
    float g[4]  = {gv.x, gv.y, gv.z, gv.w};
    float bl[4] = {bv.x, bv.y, bv.z, bv.w};
    unsigned short oy[4], ocb[4], ocr[4];
#pragma unroll
    for (int i = 0; i < 4; ++i) {
        float y = 0.299f * r[i] + 0.587f * g[i] + 0.114f * bl[i];
        oy[i]  = f2bf(2.0f * y - 1.0f);          // 2*y - 1
        ocb[i] = f2bf((bl[i] - y) * 1.128f);     // 2*((b-y)*0.564+0.5) - 1
        ocr[i] = f2bf((r[i] - y) * 1.426f);      // 2*((r-y)*0.713+0.5) - 1
    }
    *(ushort4*)(X + off)          = *(ushort4*)oy;    // c=0
    *(ushort4*)(X + off + 262144) = *(ushort4*)ocb;   // c=1 (j += 256)
    *(ushort4*)(X + off + 524288) = *(ushort4*)ocr;   // c=2
}

// ---- kernel 2: kernels f32 -> bf16 with 2/32*factors[k] folded in -----------
__global__ __launch_bounds__(256) void prep_A(const float* __restrict__ kern,
                                              const float* __restrict__ factors,
                                              unsigned short* __restrict__ A) {
    int t = blockIdx.x * 256 + threadIdx.x;    // 1024*1024/4
    int k = t >> 8;
    float s = factors[k] * 0.0625f;
    float4 v = *(const float4*)(kern + (size_t)t * 4);
    unsigned short o[4] = {f2bf(v.x * s), f2bf(v.y * s), f2bf(v.z * s), f2bf(v.w * s)};
    *(ushort4*)(A + (size_t)t * 4) = *(ushort4*)o;
}

// ---- kernel 3: GEMM, m97 structure: 128x128 tile, BK=32, 4 waves 4x4 mfma ---
__global__ __launch_bounds__(256) void gemm_kernel(const unsigned short* __restrict__ A,
                                                   const unsigned short* __restrict__ X,
                                                   float* __restrict__ out) {
    __shared__ unsigned short As[128 * 32];   // 8 KB, row-major [m][k], NO pad
    __shared__ unsigned short Bs[128 * 32];   // 8 KB, row-major [n][k], NO pad

    const int tid  = threadIdx.x;
    const int lane = tid & 63;
    const int wave = tid >> 6;
    const int wm   = wave & 1;     // wave's 64-row block of M
    const int wn   = wave >> 1;    // wave's 64-col block of N
    const int quad = lane >> 4;
    const int l15  = lane & 15;
    const int bm   = blockIdx.x;   // 0..7
    const int bn   = blockIdx.y;   // 0..191

    // staging slots: slot s covers row s>>2, k-bytes (s&3)*16; LDS byte off = s*16
    const int s0 = tid, s1 = tid + 256;
    const unsigned short* Ag0 = A + (size_t)(bm * 128 + (s0 >> 2)) * 1024 + (s0 & 3) * 8;
    const unsigned short* Ag1 = A + (size_t)(bm * 128 + (s1 >> 2)) * 1024 + (s1 & 3) * 8;
    const unsigned short* Bg0 = X + (size_t)(bn * 128 + (s0 >> 2)) * 1024 + (s0 & 3) * 8;
    const unsigned short* Bg1 = X + (size_t)(bn * 128 + (s1 >> 2)) * 1024 + (s1 & 3) * 8;
    // wave-uniform LDS bases (HW adds lane*16 bytes)
    unsigned short* lA0 = As + (size_t)(tid & 192) * 8;
    unsigned short* lA1 = As + ((size_t)(tid & 192) + 256) * 8;
    unsigned short* lB0 = Bs + (size_t)(tid & 192) * 8;
    unsigned short* lB1 = Bs + ((size_t)(tid & 192) + 256) * 8;

    f32x4 acc[4][4];
#pragma unroll
    for (int i = 0; i < 4; ++i)
#pragma unroll
        for (int j = 0; j < 4; ++j)
            acc[i][j] = (f32x4){0.f, 0.f, 0.f, 0.f};

    for (int kt = 0; kt < 32; ++kt) {
        GLOAD_LDS16(Ag0, lA0);
        GLOAD_LDS16(Ag1, lA1);
        GLOAD_LDS16(Bg0, lB0);
        GLOAD_LDS16(Bg1, lB1);
        Ag0 += 32; Ag1 += 32; Bg0 += 32; Bg1 += 32;
        __syncthreads();   // drains vmcnt -> LDS tiles ready

        bf16x8 af[4], bfr[4];
#pragma unroll
        for (int i = 0; i < 4; ++i) {
            af[i]  = *(const bf16x8*)(As + (wm * 64 + i * 16 + l15) * 32 + quad * 8);
            bfr[i] = *(const bf16x8*)(Bs + (wn * 64 + i * 16 + l15) * 32 + quad * 8);
        }
#pragma unroll
        for (int i = 0; i < 4; ++i)
#pragma unroll
            for (int j = 0; j < 4; ++j)
                acc[i][j] = __builtin_amdgcn_mfma_f32_16x16x32_bf16(af[i], bfr[j], acc[i][j], 0, 0, 0);
        __syncthreads();   // all reads done before next stage overwrites
    }

    // epilogue: D row = kcoef (quad*4+r), D col = j (l15); 128-wide N tile
    // stays inside one bc block (bc blocks are 256-aligned in j)
    const int bc   = (bn * 128) >> 8;
    const int jbase = bn * 128 + wn * 64 + l15;
#pragma unroll
    for (int i = 0; i < 4; ++i) {
        int kc = bm * 128 + wm * 64 + i * 16 + quad * 4;
#pragma unroll
        for (int j = 0; j < 4; ++j) {
            int mn = (jbase + j * 16) & 255;
            float* po = out + (size_t)bc * 262144 + (size_t)kc * 256 + mn;
            f32x4 v = acc[i][j];
#pragma unroll
            for (int r = 0; r < 4; ++r)
                po[(size_t)r * 256] = v[r];
        }
    }
}

extern "C" void kernel_launch(void* const* d_in, const int* in_sizes, int n_in,
                              void* d_out, int out_size, void* d_ws, size_t ws_size,
                              hipStream_t stream) {
    const float* rgb     = (const float*)d_in[0];  // (32,3,512,512)
    const float* kern    = (const float*)d_in[1];  // (1024,32,32)
    const float* factors = (const float*)d_in[2];  // (1024,)
    float* out = (float*)d_out;                    // (32,3072,16,16)

    unsigned short* X  = (unsigned short*)d_ws;              // 24576*1024 bf16 = 50.3 MB
    unsigned short* Ab = X + (size_t)24576 * 1024;           // 1024*1024 bf16 = 2 MB

    prep_kernel<<<8192, 256, 0, stream>>>(rgb, X);
    prep_A<<<1024, 256, 0, stream>>>(kern, factors, Ab);
    gemm_kernel<<<dim3(8, 192), 256, 0, stream>>>(Ab, X, out);
}

// Round 3
// 234.467 us; speedup vs baseline: 1.1009x; 1.1009x over previous
//
#include <hip/hip_runtime.h>
#include <math.h>

// DCT encoder, separable form. kernels[k] = outer(cv_k, cu_k) with
// cv[i]=cos((2i+1)v pi/64) on ROWS (i), cu[j] on COLUMNS (j)  [meshgrid 'xy'].
// Stage1 contracts y=cols with freq f1==u; stage2 contracts x=rows with f2==v.
// Output coefficient index: P[f2*32 + f1]  (P recovered analytically in setup).
// Total HBM traffic ~201 MB (read rgb + write out); intermediates in reg/LDS.

typedef __bf16 bf16x8 __attribute__((ext_vector_type(8)));
typedef float  f32x4  __attribute__((ext_vector_type(4)));

#define PI_F 3.14159265358979323846f

__device__ __forceinline__ unsigned short f2bf(float f) {
    union { float f; unsigned u; } v; v.f = f;
    unsigned u = v.u;
    u += 0x7fffu + ((u >> 16) & 1u);   // round-to-nearest-even
    return (unsigned short)(u >> 16);
}

// ---- K0: build cos table (bf16), permutation P, scales S --------------------
// kern[k][i][j] = cos((2j+1)u pi/64) * cos((2i+1)v pi/64), k sorted by |(v,u)|.
// Recover v from K[1][0]/K[0][0] = cos(3t)/cos(t) = 4cos^2(t)-3, t=v*pi/64;
// u likewise from K[0][1]/K[0][0].
__global__ __launch_bounds__(256) void setup_kernel(const float* __restrict__ kern,
                                                    const float* __restrict__ factors,
                                                    unsigned short* __restrict__ Cbf,
                                                    int* __restrict__ P,
                                                    float* __restrict__ S) {
    int k = blockIdx.x * 256 + threadIdx.x;   // 0..1023
    // cos table: Cbf[t*32+i] = bf16(cos((2i+1)*t*pi/64))
    int i = k & 31, t = k >> 5;
    Cbf[k] = f2bf(cosf((float)((2 * i + 1) * t) * (PI_F / 64.f)));

    float k00 = kern[(size_t)k * 1024];              // cv[0]*cu[0] > 0 always
    float rv  = kern[(size_t)k * 1024 + 32] / k00;   // K[1][0]/K[0][0] -> v
    float ru  = kern[(size_t)k * 1024 + 1]  / k00;   // K[0][1]/K[0][0] -> u
    float cv2 = fminf(fmaxf((rv + 3.f) * 0.25f, 0.f), 1.f);
    float cu2 = fminf(fmaxf((ru + 3.f) * 0.25f, 0.f), 1.f);
    int v = __float2int_rn(acosf(sqrtf(cv2)) * (64.f / PI_F));
    int u = __float2int_rn(acosf(sqrtf(cu2)) * (64.f / PI_F));
    P[v * 32 + u] = k;
    S[k] = factors[k] * (2.f / 32.f);
}

// ---- fused kernel: one block per (b, m) strip of 16 DCT blocks --------------
// Stage1: T[f1][n][x] = sum_y C[f1][y] * ycbcr[c][m*32+x][n*32+y]   (MFMA, K=32)
// Stage2: out[bc][P[f2*32+f1]][m*16+n] = S * sum_x C[f2][x] * T[f1][n][x]
// LDS T layout: row (f1,n): 80 B (32 bf16 + 16 pad), f1-stride 1280 B -> 40 KB.
__global__ __launch_bounds__(512, 2) void dct_fused(const float* __restrict__ rgb,
                                                    const unsigned short* __restrict__ Cbf,
                                                    const int* __restrict__ P,
                                                    const float* __restrict__ S,
                                                    float* __restrict__ out) {
    __shared__ __align__(16) unsigned char Tls[32 * 1280];   // 40 KB

    const int tid  = threadIdx.x;
    const int lane = tid & 63;
    const int w    = tid >> 6;        // wave 0..7, owns x = w*4..w*4+3
    const int quad = lane >> 4;
    const int l15  = lane & 15;
    const int b    = blockIdx.x >> 4;
    const int m    = blockIdx.x & 15;

    // A-operand frags (shared by both stages): A[m=l15][k=quad*8+j] = C[row][col]
    union { bf16x8 v; unsigned short s[8]; } af0, af1;
    af0.v = *(const bf16x8*)(Cbf + l15 * 32 + quad * 8);
    af1.v = *(const bf16x8*)(Cbf + (16 + l15) * 32 + quad * 8);

    const f32x4 zero = {0.f, 0.f, 0.f, 0.f};
    f32x4 d[3][2][4];   // [c][f1-half][xi], row f1=fh*16+quad*4+r, col n=l15

    // ---- stage 1 ----
    const float* rbase = rgb + (size_t)b * 786432 + (size_t)l15 * 32 + (size_t)quad * 8;
#pragma unroll
    for (int xi = 0; xi < 4; ++xi) {
        const int x = w * 4 + xi;
        const float* p = rbase + (size_t)(m * 32 + x) * 512;
        float4 R0 = *(const float4*)(p);
        float4 R1 = *(const float4*)(p + 4);
        float4 G0 = *(const float4*)(p + 262144);
        float4 G1 = *(const float4*)(p + 262148);
        float4 B0 = *(const float4*)(p + 524288);
        float4 B1 = *(const float4*)(p + 524292);
        float R[8]  = {R0.x, R0.y, R0.z, R0.w, R1.x, R1.y, R1.z, R1.w};
        float G[8]  = {G0.x, G0.y, G0.z, G0.w, G1.x, G1.y, G1.z, G1.w};
        float Bv[8] = {B0.x, B0.y, B0.z, B0.w, B1.x, B1.y, B1.z, B1.w};
        union { bf16x8 v; unsigned short s[8]; } fy, fcb, fcr;
#pragma unroll
        for (int e = 0; e < 8; ++e) {
            float y = 0.299f * R[e] + 0.587f * G[e] + 0.114f * Bv[e];
            fy.s[e]  = f2bf(2.f * y - 1.f);           // 2*Y - 1
            fcb.s[e] = f2bf(1.128f * (Bv[e] - y));    // 2*((b-y)*.564+.5) - 1
            fcr.s[e] = f2bf(1.426f * (R[e] - y));     // 2*((r-y)*.713+.5) - 1
        }
        d[0][0][xi] = __builtin_amdgcn_mfma_f32_16x16x32_bf16(af0.v, fy.v,  zero, 0, 0, 0);
        d[0][1][xi] = __builtin_amdgcn_mfma_f32_16x16x32_bf16(af1.v, fy.v,  zero, 0, 0, 0);
        d[1][0][xi] = __builtin_amdgcn_mfma_f32_16x16x32_bf16(af0.v, fcb.v, zero, 0, 0, 0);
        d[1][1][xi] = __builtin_amdgcn_mfma_f32_16x16x32_bf16(af1.v, fcb.v, zero, 0, 0, 0);
        d[2][0][xi] = __builtin_amdgcn_mfma_f32_16x16x32_bf16(af0.v, fcr.v, zero, 0, 0, 0);
        d[2][1][xi] = __builtin_amdgcn_mfma_f32_16x16x32_bf16(af1.v, fcr.v, zero, 0, 0, 0);
    }

    // ---- stage 2, channel-sequential (keeps LDS at 40 KB) ----
    const size_t obase0 = (size_t)(b * 3) * 262144 + (size_t)m * 16 + (size_t)l15;
#pragma unroll 1
    for (int c = 0; c < 3; ++c) {
        // scatter this channel's T into LDS: T[f1][n=l15][x], x-chunk w packed b64
#pragma unroll
        for (int fh = 0; fh < 2; ++fh)
#pragma unroll
            for (int r = 0; r < 4; ++r) {
                const int f1 = fh * 16 + quad * 4 + r;
                ushort4 pk;
                pk.x = f2bf(d[c][fh][0][r]);
                pk.y = f2bf(d[c][fh][1][r]);
                pk.z = f2bf(d[c][fh][2][r]);
                pk.w = f2bf(d[c][fh][3][r]);
                *(ushort4*)(Tls + f1 * 1280 + l15 * 80 + w * 8) = pk;
            }
        __syncthreads();

        const size_t obase = obase0 + (size_t)c * 262144;
#pragma unroll
        for (int i = 0; i < 4; ++i) {
            const int f1 = w * 4 + i;   // stage-1 freq == u (column freq)
            bf16x8 bfr = *(const bf16x8*)(Tls + f1 * 1280 + l15 * 80 + quad * 16);
#pragma unroll
            for (int uh = 0; uh < 2; ++uh) {
                f32x4 d2 = __builtin_amdgcn_mfma_f32_16x16x32_bf16(
                    uh ? af1.v : af0.v, bfr, zero, 0, 0, 0);
                const int f2b = uh * 16 + quad * 4;   // stage-2 freq == v (row freq)
#pragma unroll
                for (int r = 0; r < 4; ++r) {
                    const int kk = P[(f2b + r) * 32 + f1];   // P[v*32+u]
                    out[obase + (size_t)kk * 256] = d2[r] * S[kk];
                }
            }
        }
        __syncthreads();   // T reads done before next channel overwrites
    }
}

extern "C" void kernel_launch(void* const* d_in, const int* in_sizes, int n_in,
                              void* d_out, int out_size, void* d_ws, size_t ws_size,
                              hipStream_t stream) {
    const float* rgb     = (const float*)d_in[0];  // (32,3,512,512)
    const float* kern    = (const float*)d_in[1];  // (1024,32,32)
    const float* factors = (const float*)d_in[2];  // (1024,)
    float* out = (float*)d_out;                    // (32,3072,16,16)

    unsigned short* Cbf = (unsigned short*)d_ws;          // 2 KB
    int*   P = (int*)((char*)d_ws + 8192);                // 4 KB
    float* S = (float*)((char*)d_ws + 12288);             // 4 KB

    setup_kernel<<<4, 256, 0, stream>>>(kern, factors, Cbf, P, S);
    dct_fused<<<512, 512, 0, stream>>>(rgb, Cbf, P, S, out);
}

// Round 4
// 218.801 us; speedup vs baseline: 1.1797x; 1.0716x over previous
//
#include <hip/hip_runtime.h>
#include <math.h>

// DCT encoder, separable form. kernels[k] = outer(cv_k, cu_k) with
// cv[i]=cos((2i+1)v pi/64) on ROWS (i), cu[j] on COLUMNS (j)  [meshgrid 'xy'].
// Stage1 contracts y=cols with freq f1==u; stage2 contracts x=rows with f2==v.
// Output coefficient index: T2[f2*32+f1] = {k, scale}  (recovered in setup).
// R4: transient stage-1 accumulators (occupancy), XCD m-pair swizzle (L2 write
// merge), fused P/S table.

typedef __bf16 bf16x8 __attribute__((ext_vector_type(8)));
typedef float  f32x4  __attribute__((ext_vector_type(4)));

#define PI_F 3.14159265358979323846f

__device__ __forceinline__ unsigned short f2bf(float f) {
    union { float f; unsigned u; } v; v.f = f;
    unsigned u = v.u;
    u += 0x7fffu + ((u >> 16) & 1u);   // round-to-nearest-even
    return (unsigned short)(u >> 16);
}

// ---- K0: cos table (bf16) + fused {k, scale} table --------------------------
// kern[k][i][j] = cos((2j+1)u pi/64) * cos((2i+1)v pi/64), k sorted by |(v,u)|.
// v from K[1][0]/K[0][0] = 4cos^2(v pi/64)-3; u from K[0][1]/K[0][0].
__global__ __launch_bounds__(256) void setup_kernel(const float* __restrict__ kern,
                                                    const float* __restrict__ factors,
                                                    unsigned short* __restrict__ Cbf,
                                                    int2* __restrict__ T2) {
    int k = blockIdx.x * 256 + threadIdx.x;   // 0..1023
    int i = k & 31, t = k >> 5;
    Cbf[k] = f2bf(cosf((float)((2 * i + 1) * t) * (PI_F / 64.f)));

    float k00 = kern[(size_t)k * 1024];              // cv[0]*cu[0] > 0 always
    float rv  = kern[(size_t)k * 1024 + 32] / k00;   // -> v
    float ru  = kern[(size_t)k * 1024 + 1]  / k00;   // -> u
    float cv2 = fminf(fmaxf((rv + 3.f) * 0.25f, 0.f), 1.f);
    float cu2 = fminf(fmaxf((ru + 3.f) * 0.25f, 0.f), 1.f);
    int v = __float2int_rn(acosf(sqrtf(cv2)) * (64.f / PI_F));
    int u = __float2int_rn(acosf(sqrtf(cu2)) * (64.f / PI_F));
    float s = factors[k] * (2.f / 32.f);
    T2[v * 32 + u] = make_int2(k, __float_as_int(s));
}

// ---- fused kernel: one block per (b, m) strip of 16 DCT blocks --------------
// Stage1: T[f1][n][x] = sum_y C[f1][y] * ycbcr[c][m*32+x][n*32+y]   (MFMA, K=32)
// Stage2: out[bc][T2[f2*32+f1].k][m*16+n] = s * sum_x C[f2][x] * T[f1][n][x]
// LDS T row (f1,n): 80 B (32 bf16 + 16 pad), f1-stride 1280 B -> 40 KB.
__global__ __launch_bounds__(512, 4) void dct_fused(const float* __restrict__ rgb,
                                                    const unsigned short* __restrict__ Cbf,
                                                    const int2* __restrict__ T2,
                                                    float* __restrict__ out) {
    __shared__ __align__(16) unsigned char Tls[32 * 1280];   // 40 KB

    const int tid  = threadIdx.x;
    const int lane = tid & 63;
    const int w    = tid >> 6;        // wave 0..7, owns x = w*4..w*4+3
    const int quad = lane >> 4;
    const int l15  = lane & 15;
    // XCD-pair swizzle: blocks g and g+8 (same XCD under %8 round-robin)
    // handle m = 2t and 2t+1 -> their half-128B output lines merge in L2.
    const int b    = blockIdx.x >> 4;
    const int loc  = blockIdx.x & 15;
    const int m    = ((loc & 7) << 1) | (loc >> 3);

    // A-operand frags (both stages): A[row=l15][k=quad*8+j] = C[row][pos]
    union { bf16x8 v; unsigned short s[8]; } af0, af1;
    af0.v = *(const bf16x8*)(Cbf + l15 * 32 + quad * 8);
    af1.v = *(const bf16x8*)(Cbf + (16 + l15) * 32 + quad * 8);

    const f32x4 zero = {0.f, 0.f, 0.f, 0.f};

    // ---- stage 1a: load rgb once, keep ycbcr bf16 fragments (48 VGPR) ----
    bf16x8 fr[3][4];   // [c][xi]
    const float* rbase = rgb + (size_t)b * 786432 + (size_t)l15 * 32 + (size_t)quad * 8;
#pragma unroll
    for (int xi = 0; xi < 4; ++xi) {
        const int x = w * 4 + xi;
        const float* p = rbase + (size_t)(m * 32 + x) * 512;
        float4 R0 = *(const float4*)(p);
        float4 R1 = *(const float4*)(p + 4);
        float4 G0 = *(const float4*)(p + 262144);
        float4 G1 = *(const float4*)(p + 262148);
        float4 B0 = *(const float4*)(p + 524288);
        float4 B1 = *(const float4*)(p + 524292);
        float R[8]  = {R0.x, R0.y, R0.z, R0.w, R1.x, R1.y, R1.z, R1.w};
        float G[8]  = {G0.x, G0.y, G0.z, G0.w, G1.x, G1.y, G1.z, G1.w};
        float Bv[8] = {B0.x, B0.y, B0.z, B0.w, B1.x, B1.y, B1.z, B1.w};
        union { bf16x8 v; unsigned short s[8]; } fy, fcb, fcr;
#pragma unroll
        for (int e = 0; e < 8; ++e) {
            float y = 0.299f * R[e] + 0.587f * G[e] + 0.114f * Bv[e];
            fy.s[e]  = f2bf(2.f * y - 1.f);           // 2*Y - 1
            fcb.s[e] = f2bf(1.128f * (Bv[e] - y));    // 2*((b-y)*.564+.5) - 1
            fcr.s[e] = f2bf(1.426f * (R[e] - y));     // 2*((r-y)*.713+.5) - 1
        }
        fr[0][xi] = fy.v;
        fr[1][xi] = fcb.v;
        fr[2][xi] = fcr.v;
    }

    // ---- per channel: stage-1 MFMAs (transient acc) -> LDS -> stage 2 ----
    const size_t obase0 = (size_t)(b * 3) * 262144 + (size_t)m * 16 + (size_t)l15;
#pragma unroll
    for (int c = 0; c < 3; ++c) {
#pragma unroll
        for (int fh = 0; fh < 2; ++fh) {
            f32x4 dd[4];
#pragma unroll
            for (int xi = 0; xi < 4; ++xi)
                dd[xi] = __builtin_amdgcn_mfma_f32_16x16x32_bf16(
                    fh ? af1.v : af0.v, fr[c][xi], zero, 0, 0, 0);
            // scatter: T[f1][n=l15][x-chunk w], rows f1 = fh*16+quad*4+r
#pragma unroll
            for (int r = 0; r < 4; ++r) {
                const int f1 = fh * 16 + quad * 4 + r;
                ushort4 pk;
                pk.x = f2bf(dd[0][r]);
                pk.y = f2bf(dd[1][r]);
                pk.z = f2bf(dd[2][r]);
                pk.w = f2bf(dd[3][r]);
                *(ushort4*)(Tls + f1 * 1280 + l15 * 80 + w * 8) = pk;
            }
        }
        __syncthreads();

        const size_t obase = obase0 + (size_t)c * 262144;
#pragma unroll
        for (int i = 0; i < 4; ++i) {
            const int f1 = w * 4 + i;   // stage-1 freq == u (column freq)
            bf16x8 bfr = *(const bf16x8*)(Tls + f1 * 1280 + l15 * 80 + quad * 16);
#pragma unroll
            for (int uh = 0; uh < 2; ++uh) {
                f32x4 d2 = __builtin_amdgcn_mfma_f32_16x16x32_bf16(
                    uh ? af1.v : af0.v, bfr, zero, 0, 0, 0);
                const int f2b = uh * 16 + quad * 4;   // stage-2 freq == v (row freq)
#pragma unroll
                for (int r = 0; r < 4; ++r) {
                    int2 ks = T2[(f2b + r) * 32 + f1];   // {k, scale}
                    out[obase + (size_t)ks.x * 256] = d2[r] * __int_as_float(ks.y);
                }
            }
        }
        __syncthreads();   // T reads done before next channel overwrites
    }
}

extern "C" void kernel_launch(void* const* d_in, const int* in_sizes, int n_in,
                              void* d_out, int out_size, void* d_ws, size_t ws_size,
                              hipStream_t stream) {
    const float* rgb     = (const float*)d_in[0];  // (32,3,512,512)
    const float* kern    = (const float*)d_in[1];  // (1024,32,32)
    const float* factors = (const float*)d_in[2];  // (1024,)
    float* out = (float*)d_out;                    // (32,3072,16,16)

    unsigned short* Cbf = (unsigned short*)d_ws;          // 2 KB
    int2* T2 = (int2*)((char*)d_ws + 8192);               // 8 KB

    setup_kernel<<<4, 256, 0, stream>>>(kern, factors, Cbf, T2);
    dct_fused<<<512, 512, 0, stream>>>(rgb, Cbf, T2, out);
}